// Round 7
// baseline (560.823 us; speedup 1.0000x reference)
//
#include <hip/hip_runtime.h>
#include <hip/hip_bf16.h>

#define LF 64
#define NBAGS 5
#define BROWS 2048
#define OUTC 320
#define KC 2048
#define NMT 16
#define NCHUNKS 90                 // bags 1..4: 30 + 1 + 49 + 10
#define NSLOTS 178                 // 1KB-wave slots/row: 59 + 1 + 98 + 20

#define WS_HEAD 65536
#define WP_BYTES 23068672ull       // 2816 tiles * 8192 B
#define BM_OFF (WS_HEAD + WP_BYTES)
#define BM_BYTES 46661632ull       // 2048 * (7552+128+12544+2560)
#define PART_OFF (BM_OFF + BM_BYTES)
#define PART_BYTES ((size_t)NCHUNKS * BROWS * LF * 4)

typedef __attribute__((ext_vector_type(8))) short short8;
typedef __attribute__((ext_vector_type(4))) float f32x4;
typedef unsigned long long u64;

struct BagArgs {
    const int*   A[NBAGS];
    const float* W[NBAGS];
    int K[NBAGS];
    int cstart[NBAGS + 1];   // KC-chunk prefix, bags 1..4
    int tstart[NBAGS + 1];   // 64-k tile prefix, all bags
    int bmoff[NBAGS];        // bitmask byte offset per bag (within bm region)
    int rs[NBAGS];           // bitmask row stride, bytes
};

__device__ __forceinline__ unsigned short f2bf(float f) {
    unsigned u = __float_as_uint(f);
    u += 0x7FFFu + ((u >> 16) & 1u);   // round-to-nearest-even
    return (unsigned short)(u >> 16);
}

// Pack W (f32 [K][64]) -> bf16 tiles of 64 k (8 KB), permuted so the B
// fragment matches A where lane (fr,kg), frag m holds k = kg*16+m*8+[0..8).
// k -> block = ((k>>3)&1)*4 + (k>>4);  short idx = (block*64 + c)*8 + (k&7).
// Zero-filled past K.  [validated R5/R6]
__global__ __launch_bounds__(256) void pack_w(BagArgs args,
                                              unsigned short* __restrict__ Wp) {
    __shared__ unsigned short ls[4][4096];
    const int wv = threadIdx.x >> 6;
    const int c  = threadIdx.x & 63;
    const int gtile = blockIdx.x * 4 + wv;

    int bag = 0;
#pragma unroll
    for (int b = 1; b < NBAGS; ++b)
        if (gtile >= args.tstart[b]) bag = b;
    const int lt = gtile - args.tstart[bag];
    const float* __restrict__ W = args.W[bag];
    const int K = args.K[bag];

    unsigned short* L = ls[wv];
#pragma unroll 8
    for (int k = 0; k < 64; ++k) {
        const int gk = lt * 64 + k;
        float v = (gk < K) ? W[(size_t)gk * LF + c] : 0.f;
        const int block = ((k >> 3) & 1) * 4 + (k >> 4);
        L[(block * LF + c) * 8 + (k & 7)] = f2bf(v);
    }
    __syncthreads();
    unsigned short* dst = Wp + ((size_t)gtile << 12);
#pragma unroll
    for (int j = 0; j < 8; ++j)
        *(short8*)(dst + c * 8 + j * 512) = *(const short8*)(L + c * 8 + j * 512);
}

// Pass 1: copy-shaped. Each wave reads 4 KB SEQUENTIAL from one row of one
// bag, emits 128 B of bitmask (1 bit/elem, lane-major nibble packing) and
// one exact int popcount atomic. Rows padded to 1024-bit multiples (zeros).
__global__ __launch_bounds__(256) void compress(BagArgs args,
                                                unsigned char* __restrict__ bm,
                                                int* __restrict__ sums) {
    const int wv = threadIdx.x >> 6;
    const int lane = threadIdx.x & 63;
    const int slot = blockIdx.x * 4 + wv;
    if (slot >= NSLOTS) return;
    int bag, s0;
    if      (slot >= 158) { bag = 4; s0 = 158; }
    else if (slot >=  60) { bag = 3; s0 = 60;  }
    else if (slot >=  59) { bag = 2; s0 = 59;  }
    else                  { bag = 1; s0 = 0;   }
    const int w   = slot - s0;
    const int row = blockIdx.y;
    const int K   = args.K[bag];
    const int kb  = w * 1024;
    const int* __restrict__ A = args.A[bag] + (size_t)row * K;
    unsigned char* __restrict__ dst =
        bm + args.bmoff[bag] + (size_t)row * args.rs[bag] + w * 128;

    int cnt = 0;
#pragma unroll
    for (int s = 0; s < 4; ++s) {
        const int k = kb + s * 256 + lane * 4;   // K%4==0: int4 fully in/out
        int4 v = make_int4(0, 0, 0, 0);
        if (k < K) v = *(const int4*)(A + k);
        cnt += v.x + v.y + v.z + v.w;            // ints are exactly {0,1}
        const unsigned nib = (unsigned)(v.x | (v.y << 1) | (v.z << 2) | (v.w << 3));
        u64 u = (u64)nib << ((lane & 15) * 4);
        u |= __shfl_xor(u, 1);
        u |= __shfl_xor(u, 2);
        u |= __shfl_xor(u, 4);
        u |= __shfl_xor(u, 8);
        if ((lane & 15) == 0)                    // lanes 0,16,32,48
            *(u64*)(dst + s * 32 + (lane >> 4) * 8) = u;
    }
    cnt += __shfl_xor(cnt, 1);
    cnt += __shfl_xor(cnt, 2);
    cnt += __shfl_xor(cnt, 4);
    cnt += __shfl_xor(cnt, 8);
    cnt += __shfl_xor(cnt, 16);
    cnt += __shfl_xor(cnt, 32);
    if (lane == 0) atomicAdd(&sums[bag * BROWS + row], cnt);
}

// Pass 2: MFMA GEMM off the bitmask. A = 2 u64/lane/superstep (L3-resident),
// expanded to bf16 in-register; B = packed Wp fragments (L2). R4's validated
// explicit ping-pong + sched_barrier structure; no LDS, no barriers.
__global__ __launch_bounds__(256) void bag_gemm(BagArgs args,
                                                const unsigned short* __restrict__ Wp,
                                                const unsigned char* __restrict__ bm,
                                                float* __restrict__ part)
{
    const int tid  = threadIdx.x;
    const int wave = tid >> 6;
    const int lane = tid & 63;
    const int fr   = lane & 15;
    const int kg   = lane >> 4;

    const int g  = blockIdx.x >> 4;
    const int mt = blockIdx.x & 15;

    int bag = 1;
#pragma unroll
    for (int b = 2; b < NBAGS; ++b)
        if (g >= args.cstart[b]) bag = b;
    const int chunk  = g - args.cstart[bag];
    const int K      = args.K[bag];
    const int kc0    = chunk * KC;
    const int ksz    = min(kc0 + KC, K) - kc0;
    const int nsuper = (ksz + 63) >> 6;          // bm rows padded: no masking

    const int row0 = mt * 128 + wave * 32;
    const unsigned char* __restrict__ pb0 =
        bm + args.bmoff[bag] + (size_t)(row0 + fr) * args.rs[bag] + (kc0 >> 3);
    const unsigned char* __restrict__ pb1 = pb0 + (size_t)16 * args.rs[bag];
    const unsigned short* __restrict__ pB =
        Wp + ((size_t)(args.tstart[bag] + chunk * (KC / 64)) << 12) + (kg * LF + fr) * 8;

    f32x4 acc0[4], acc1[4];
#pragma unroll
    for (int i = 0; i < 4; ++i) {
        acc0[i] = (f32x4){0.f, 0.f, 0.f, 0.f};
        acc1[i] = (f32x4){0.f, 0.f, 0.f, 0.f};
    }

    auto loadA = [&](int ss, u64& x0, u64& x1) {
        x0 = *(const u64*)(pb0 + ss * 8);
        x1 = *(const u64*)(pb1 + ss * 8);
    };
    auto loadB = [&](int ss, short8 (&y)[2][4]) {
        const unsigned short* p = pB + (size_t)ss * 4096;
#pragma unroll
        for (int m = 0; m < 2; ++m)
#pragma unroll
            for (int ni = 0; ni < 4; ++ni)
                y[m][ni] = *(const short8*)(p + m * 2048 + ni * 128);
    };

    // 2 bits -> dword of 2 bf16 (0x3F80 = bf16(1)): (b&2)*0x1FC00000 = b1<<...
    auto bf16pair = [](unsigned b) -> int {
        return (int)((b & 1u) * 0x3F80u + (b & 2u) * 0x1FC00000u);
    };
    auto mkfrag = [&](unsigned byte) -> short8 {
        int4 u = make_int4(bf16pair(byte), bf16pair(byte >> 2),
                           bf16pair(byte >> 4), bf16pair(byte >> 6));
        return *(short8*)&u;
    };
    auto compute = [&](u64 x0, u64 x1, const short8 (&y)[2][4]) {
        const unsigned lo0 = (unsigned)(x0 >> (kg * 16));
        const unsigned lo1 = (unsigned)(x1 >> (kg * 16));
#pragma unroll
        for (int m = 0; m < 2; ++m) {
            const short8 fa0 = mkfrag((lo0 >> (m * 8)) & 0xFFu);
            const short8 fa1 = mkfrag((lo1 >> (m * 8)) & 0xFFu);
#pragma unroll
            for (int ni = 0; ni < 4; ++ni) {
                acc0[ni] = __builtin_amdgcn_mfma_f32_16x16x32_bf16(fa0, y[m][ni], acc0[ni], 0, 0, 0);
                acc1[ni] = __builtin_amdgcn_mfma_f32_16x16x32_bf16(fa1, y[m][ni], acc1[ni], 0, 0, 0);
            }
        }
    };

    u64 Aa0, Aa1, Ab0, Ab1;
    short8 Ba[2][4], Bb[2][4];
    loadA(0, Aa0, Aa1);
    loadB(0, Ba);
    const int npair = (nsuper + 1) >> 1;
    for (int p = 0; p < npair; ++p) {
        const int s1  = 2 * p + 1;
        const int s1c = min(s1, nsuper - 1);
        loadA(s1c, Ab0, Ab1);
        loadB(s1c, Bb);
        __builtin_amdgcn_sched_barrier(0);
        compute(Aa0, Aa1, Ba);                  // step 2p (always valid)
        const int s2c = min(2 * p + 2, nsuper - 1);
        loadA(s2c, Aa0, Aa1);
        loadB(s2c, Ba);
        __builtin_amdgcn_sched_barrier(0);
        if (s1 < nsuper)                        // uniform pad guard
            compute(Ab0, Ab1, Bb);
    }

    // C/D: col = lane&15 (=fr), row = kg*4 + reg   [validated R1-R6]
    float* dst = part + ((size_t)g * BROWS + row0 + kg * 4) * LF + fr;
#pragma unroll
    for (int ni = 0; ni < 4; ++ni)
#pragma unroll
        for (int r = 0; r < 4; ++r) {
            dst[(size_t)(r) * LF + ni * 16]      = acc0[ni][r];
            dst[(size_t)(16 + r) * LF + ni * 16] = acc1[ni][r];
        }
}

// Sum split-K partials, normalize (incl. faithful "decades divided twice"
// bug), and compute the tiny K=12 decades bag directly in f32.
__global__ __launch_bounds__(256) void reduce_norm(BagArgs args,
                                                   const float* __restrict__ part,
                                                   float* __restrict__ out,
                                                   const int* __restrict__ sums)
{
    const int idx = blockIdx.x * 256 + threadIdx.x;
    if (idx >= BROWS * OUTC) return;
    const int row = idx / OUTC;
    const int c   = idx - row * OUTC;
    const int bag = c >> 6;
    const int col = c & 63;

    float v;
    if (bag == 0) {
        const int*   A0 = args.A[0];
        const float* W0 = args.W[0];
        float a = 0.f; int s = 0;
#pragma unroll
        for (int k = 0; k < 12; ++k) {
            const int x = A0[row * 12 + k];
            s += x;
            if (x) a += W0[k * LF + col];
        }
        if (s) a /= (float)s;
        const int sm = sums[1 * BROWS + row];   // ref bug: also divide by movie sum
        if (sm) a /= (float)sm;
        v = a;
    } else {
        float a = 0.f;
        for (int gg = args.cstart[bag]; gg < args.cstart[bag + 1]; ++gg)
            a += part[((size_t)gg * BROWS + row) * LF + col];
        v = a;
        if (bag >= 2) {
            const int s = sums[bag * BROWS + row];
            if (s) v /= (float)s;
        }
        // bag 1 (movies): never normalized (faithful to reference bug)
    }
    out[idx] = v;
}

// Correctness-only fallback (tiny ws): one thread per output element.
__global__ void naive_bag(BagArgs args, float* __restrict__ out) {
    const int row = blockIdx.x;
    const int c   = threadIdx.x;
    if (c >= OUTC) return;
    const int bag = c >> 6;
    const int col = c & 63;
    const int K = args.K[bag];
    const int* A = args.A[bag] + (size_t)row * K;
    const float* W = args.W[bag];
    float a = 0.f; int s = 0;
    for (int k = 0; k < K; ++k) {
        const int x = A[k];
        s += x;
        if (x) a += W[(size_t)k * LF + col];
    }
    if (bag != 1 && s) a /= (float)s;
    if (bag == 0) {
        const int* A1 = args.A[1] + (size_t)row * args.K[1];
        int sm = 0;
        for (int k = 0; k < args.K[1]; ++k) sm += A1[k];
        if (sm) a /= (float)sm;
    }
    out[(size_t)row * OUTC + c] = a;
}

extern "C" void kernel_launch(void* const* d_in, const int* in_sizes, int n_in,
                              void* d_out, int out_size, void* d_ws, size_t ws_size,
                              hipStream_t stream) {
    float* out = (float*)d_out;
    int* sums = (int*)d_ws;
    unsigned short* Wp = (unsigned short*)((char*)d_ws + WS_HEAD);
    unsigned char* bm  = (unsigned char*)((char*)d_ws + BM_OFF);
    float* part = (float*)((char*)d_ws + PART_OFF);

    BagArgs args;
    const int Ks[NBAGS] = {12, 60000, 32, 100000, 20000};
    int tcum = 0;
    for (int b = 0; b < NBAGS; ++b) {
        args.A[b] = (const int*)d_in[b];
        args.W[b] = (const float*)d_in[5 + b];
        args.K[b] = Ks[b];
        args.tstart[b] = tcum;
        tcum += (Ks[b] + 63) / 64;          // -> 2816
    }
    args.tstart[NBAGS] = tcum;
    args.cstart[0] = 0;
    int ccum = 0;
    for (int b = 1; b < NBAGS; ++b) {
        args.cstart[b] = ccum;
        ccum += (Ks[b] + KC - 1) / KC;      // 30 + 1 + 49 + 10 = 90
    }
    args.cstart[NBAGS] = ccum;

    // bitmask geometry: rows padded to 1024-bit multiples
    args.rs[0] = 0;
    int bcum = 0;
    for (int b = 1; b < NBAGS; ++b) {
        args.rs[b] = ((Ks[b] + 1023) / 1024) * 128;   // 7552,128,12544,2560
        args.bmoff[b] = bcum;
        bcum += BROWS * args.rs[b];
    }
    args.bmoff[0] = 0;

    const bool ok = ws_size >= PART_OFF + PART_BYTES;
    if (!ok) {
        naive_bag<<<BROWS, OUTC, 0, stream>>>(args, out);
        return;
    }

    hipMemsetAsync(sums, 0, NBAGS * BROWS * sizeof(int), stream);

    pack_w<<<tcum / 4, 256, 0, stream>>>(args, Wp);
    compress<<<dim3((NSLOTS + 3) / 4, BROWS), 256, 0, stream>>>(args, bm, sums);
    bag_gemm<<<NCHUNKS * NMT, 256, 0, stream>>>(args, Wp, bm, part);
    reduce_norm<<<(BROWS * OUTC + 255) / 256, 256, 0, stream>>>(args, part, out, sums);
}